// Round 7
// baseline (940.485 us; speedup 1.0000x reference)
//
#include <hip/hip_runtime.h>

// APPNP propagation: h <- (1-alpha) * A @ h + alpha * x, K=10 steps.
// R3: CSR gather, bf16 h buffers (1066.6). R4: nt loads REGRESSED (1270.9).
// R5: unroll x8 + bf16 xb -> 967.6. R6: padded CSR (no hist/scan) -> 885.7.
// R7: per-row col sort -> FAILED (909.7): block generations restart the col
//     sweep; no temporal alignment. R8: sort removed + unroll x16 -> 864.6,
//     but unroll gained ~0 -> spmm is THROUGHPUT-bound (425 MB/step L2-miss
//     traffic at ~5.9 TB/s fabric), not latency-bound. Build = 126 us.
// R9: two-pass bucketed CSR build replaces scatter_padded:
//     A) 196 buckets x 512 rows; per-block LDS hist -> 1 global atomic per
//        (block,bucket) (~150k vs 1.6M); 16B entries written grouped -> L2
//        merges to full lines (32KB/block footprint). gbuf aliases h_b+xb.
//     B) 64 persistent blocks; per-bucket LDS row-cursors (NO global
//        atomics), csrp writes in 256KB window x 64 concurrent = 2MB/XCD
//        -> L2-resident merge; cnt[row] written from LDS for free.
//     spmm unchanged (72 us/step; segment-sweep reuse scheme deferred).
// R10: resubmission of R9 unchanged (bench infra failed twice; source
//     re-audited: bounds, alias lifetimes, init, graph-capture all clean).

#define N_NODES 100000
#define N_EDGES 1600000
#define D_FEAT  128
#define ALPHA   0.1f
#define K_STEPS 10
#define MAXDEG  64   // P(Poisson(16) >= 64) ~ 1e-19; guarded anyway

#define NBUCK 196    // buckets of 512 rows: (N_NODES + 511) >> 9
#define BCAP  16000  // entries/bucket; mean 8192, cap ~ +86 sigma
#define EPB_A 2048   // edges per block in pass A

#define SCAN_ELEMS 512
#define SCAN_NBLK  ((N_NODES + SCAN_ELEMS - 1) / SCAN_ELEMS)  // 196

static __device__ __forceinline__ float bf2f(unsigned u16) {
    return __uint_as_float(u16 << 16);
}
static __device__ __forceinline__ unsigned f2bf(float f) {
    unsigned u = __float_as_uint(f);
    return (u + 0x7fffu + ((u >> 16) & 1u)) >> 16;  // round-to-nearest-even
}

// ---------- bucketed CSR build (tier 1) ----------

__global__ __launch_bounds__(256) void bucket_scatter(const int* __restrict__ rows,
                                                      const int* __restrict__ cols,
                                                      const float* __restrict__ w,
                                                      int* __restrict__ gcount,
                                                      int4* __restrict__ gbuf) {
    __shared__ int h_cnt[NBUCK];
    __shared__ int h_base[NBUCK];
    __shared__ int h_cur[NBUCK];
    const int tid = threadIdx.x;
    for (int i = tid; i < NBUCK; i += 256) { h_cnt[i] = 0; h_cur[i] = 0; }
    __syncthreads();

    const int base_e = blockIdx.x * EPB_A + tid;
    int er[8]; int ec[8]; float ew[8];
    #pragma unroll
    for (int k = 0; k < 8; ++k) {
        int e = base_e + k * 256;
        bool v = (e < N_EDGES);
        er[k] = v ? rows[e] : -1;
        ec[k] = v ? cols[e] : 0;
        ew[k] = v ? w[e] : 0.f;
        if (v) atomicAdd(&h_cnt[er[k] >> 9], 1);
    }
    __syncthreads();
    for (int i = tid; i < NBUCK; i += 256) {
        h_base[i] = (h_cnt[i] > 0) ? atomicAdd(&gcount[i], h_cnt[i]) : 0;
    }
    __syncthreads();
    #pragma unroll
    for (int k = 0; k < 8; ++k) {
        if (er[k] >= 0) {
            int b = er[k] >> 9;
            int p = h_base[b] + atomicAdd(&h_cur[b], 1);
            if (p < BCAP) {
                int4 ent;
                ent.x = er[k];
                ent.y = ec[k];
                ent.z = __float_as_int((1.0f - ALPHA) * ew[k]);  // fold 0.9
                ent.w = 0;
                gbuf[(size_t)b * BCAP + p] = ent;
            }
        }
    }
}

__global__ __launch_bounds__(256) void bucket_to_csr(const int* __restrict__ gcount,
                                                     const int4* __restrict__ gbuf,
                                                     int* __restrict__ cnt,
                                                     int2* __restrict__ csrp) {
    __shared__ int rcur[512];
    const int tid = threadIdx.x;
    for (int b = blockIdx.x; b < NBUCK; b += gridDim.x) {
        for (int i = tid; i < 512; i += 256) rcur[i] = 0;
        __syncthreads();
        int n = gcount[b];
        if (n > BCAP) n = BCAP;
        for (int i = tid; i < n; i += 256) {
            int4 e = gbuf[(size_t)b * BCAP + i];
            int p = atomicAdd(&rcur[e.x & 511], 1);  // LDS atomic: position
            if (p < MAXDEG) {
                int2 cw;
                cw.x = e.y;
                cw.y = e.z;
                csrp[((size_t)e.x << 6) + p] = cw;
            }
        }
        __syncthreads();
        int rowbase = b << 9;
        for (int i = tid; i < 512; i += 256) {
            int row = rowbase + i;
            if (row < N_NODES) cnt[row] = rcur[i];  // spmm clamps to MAXDEG
        }
        __syncthreads();  // protect rcur before next bucket's reset
    }
}

// ---------- compact CSR build (fallback tier, R5 path) ----------

__global__ __launch_bounds__(256) void hist_kernel(const int* __restrict__ rows,
                                                   int* __restrict__ deg) {
    int e = blockIdx.x * 256 + threadIdx.x;
    if (e < N_EDGES) atomicAdd(&deg[rows[e]], 1);
}

__global__ __launch_bounds__(256) void scan_partial(const int* __restrict__ deg,
                                                    int* __restrict__ partial) {
    __shared__ int s[256];
    int b = blockIdx.x, t = threadIdx.x;
    int i0 = b * SCAN_ELEMS + t * 2;
    int v0 = (i0 < N_NODES) ? deg[i0] : 0;
    int v1 = (i0 + 1 < N_NODES) ? deg[i0 + 1] : 0;
    s[t] = v0 + v1;
    __syncthreads();
    for (int off = 128; off > 0; off >>= 1) {
        if (t < off) s[t] += s[t + off];
        __syncthreads();
    }
    if (t == 0) partial[b] = s[0];
}

__global__ __launch_bounds__(256) void scan_top(int* __restrict__ partial) {
    __shared__ int s[256];
    int t = threadIdx.x;
    s[t] = (t < SCAN_NBLK) ? partial[t] : 0;
    __syncthreads();
    for (int off = 1; off < 256; off <<= 1) {
        int v = (t >= off) ? s[t - off] : 0;
        __syncthreads();
        s[t] += v;
        __syncthreads();
    }
    if (t < SCAN_NBLK) partial[t] = (t == 0) ? 0 : s[t - 1];
}

__global__ __launch_bounds__(256) void scan_final(int* __restrict__ deg_cursor,
                                                  const int* __restrict__ partial,
                                                  int* __restrict__ row_ptr) {
    __shared__ int s[256];
    int b = blockIdx.x, t = threadIdx.x;
    int i0 = b * SCAN_ELEMS + t * 2;
    int v0 = (i0 < N_NODES) ? deg_cursor[i0] : 0;
    int v1 = (i0 + 1 < N_NODES) ? deg_cursor[i0 + 1] : 0;
    int pair = v0 + v1;
    s[t] = pair;
    __syncthreads();
    for (int off = 1; off < 256; off <<= 1) {
        int v = (t >= off) ? s[t - off] : 0;
        __syncthreads();
        s[t] += v;
        __syncthreads();
    }
    int ex = partial[b] + s[t] - pair;  // exclusive prefix of element 2t
    if (i0 < N_NODES)     { row_ptr[i0] = ex;          deg_cursor[i0] = ex; }
    if (i0 + 1 < N_NODES) { row_ptr[i0 + 1] = ex + v0; deg_cursor[i0 + 1] = ex + v0; }
    if (b == 0 && t == 0) row_ptr[N_NODES] = N_EDGES;
}

__global__ __launch_bounds__(256) void scatter_kernel(const int* __restrict__ rows,
                                                      const int* __restrict__ cols,
                                                      const float* __restrict__ w,
                                                      int* __restrict__ cursor,
                                                      int2* __restrict__ csr) {
    int e = blockIdx.x * 256 + threadIdx.x;
    if (e < N_EDGES) {
        int pos = atomicAdd(&cursor[rows[e]], 1);
        int2 cw;
        cw.x = cols[e];
        cw.y = __float_as_int((1.0f - ALPHA) * w[e]);  // fold 0.9 into the weight
        csr[pos] = cw;
    }
}

// x fp32 -> packed 2xbf16 per u32 (row-major, 64 u32 per row)
__global__ __launch_bounds__(256) void x_to_bf16(const float2* __restrict__ x2,
                                                 unsigned* __restrict__ xb, int n) {
    int i = blockIdx.x * 256 + threadIdx.x;
    if (i < n) {
        float2 v = x2[i];
        xb[i] = f2bf(v.x) | (f2bf(v.y) << 16);
    }
}

// ---------- propagation step: one wave per row ----------
// SRC_BF/DST_BF: gather src / dst format. X_BF: alpha*x term source format.
// PAD: padded CSR (rp = cnt[], edges at row*64) vs compact (rp = row_ptr[]).

template <bool SRC_BF, bool DST_BF, bool X_BF, bool PAD>
__global__ __launch_bounds__(256) void row_spmm_t(const int* __restrict__ rp,
                                                  const int2* __restrict__ csr,
                                                  const void* __restrict__ xsrc,
                                                  const void* __restrict__ src,
                                                  void* __restrict__ dst) {
    int row = (blockIdx.x * 256 + threadIdx.x) >> 6;
    int lane = threadIdx.x & 63;
    if (row >= N_NODES) return;
    int beg, end;
    if (PAD) {
        int cn = rp[row];
        cn = (cn < MAXDEG) ? cn : MAXDEG;
        beg = row << 6;
        end = beg + cn;
    } else {
        beg = rp[row];
        end = rp[row + 1];
    }

    // x-term: issued early, overlaps the gather chain.
    float xtx, xty;
    if (X_BF) {
        unsigned u = ((const unsigned*)xsrc)[(size_t)row * 64 + lane];
        xtx = ALPHA * bf2f(u & 0xffffu);
        xty = ALPHA * bf2f(u >> 16);
    } else {
        float2 xv = ((const float2*)xsrc)[(size_t)row * 64 + lane];
        xtx = ALPHA * xv.x;
        xty = ALPHA * xv.y;
    }

    const float2*   sf = (const float2*)src;
    const unsigned* sb = (const unsigned*)src;

    float ax[4] = {0.f, 0.f, 0.f, 0.f};
    float ay[4] = {0.f, 0.f, 0.f, 0.f};

    auto gather = [&](int col) -> float2 {
        if (SRC_BF) {
            unsigned u = sb[(size_t)col * 64 + lane];
            float2 v;
            v.x = bf2f(u & 0xffffu);
            v.y = bf2f(u >> 16);
            return v;
        } else {
            return sf[(size_t)col * 64 + lane];
        }
    };

    int j = beg;
    // unroll x16: 16 outstanding 256B gathers per wave.
    while (j + 16 <= end) {
        int2 cw[16];
        #pragma unroll
        for (int u = 0; u < 16; ++u) cw[u] = csr[j + u];
        float2 v[16];
        #pragma unroll
        for (int u = 0; u < 16; ++u) v[u] = gather(cw[u].x);
        #pragma unroll
        for (int u = 0; u < 16; ++u) {
            float wv = __int_as_float(cw[u].y);
            ax[u & 3] += wv * v[u].x;
            ay[u & 3] += wv * v[u].y;
        }
        j += 16;
    }
    while (j + 8 <= end) {
        int2 cw[8];
        #pragma unroll
        for (int u = 0; u < 8; ++u) cw[u] = csr[j + u];
        float2 v[8];
        #pragma unroll
        for (int u = 0; u < 8; ++u) v[u] = gather(cw[u].x);
        #pragma unroll
        for (int u = 0; u < 8; ++u) {
            float wv = __int_as_float(cw[u].y);
            ax[u & 3] += wv * v[u].x;
            ay[u & 3] += wv * v[u].y;
        }
        j += 8;
    }
    while (j + 4 <= end) {
        int2 cw[4];
        #pragma unroll
        for (int u = 0; u < 4; ++u) cw[u] = csr[j + u];
        float2 v[4];
        #pragma unroll
        for (int u = 0; u < 4; ++u) v[u] = gather(cw[u].x);
        #pragma unroll
        for (int u = 0; u < 4; ++u) {
            float wv = __int_as_float(cw[u].y);
            ax[u] += wv * v[u].x;
            ay[u] += wv * v[u].y;
        }
        j += 4;
    }
    for (; j < end; ++j) {
        int2 cw = csr[j];
        float2 v = gather(cw.x);
        float wv = __int_as_float(cw.y);
        ax[0] += wv * v.x;
        ay[0] += wv * v.y;
    }

    float ox = xtx + (ax[0] + ax[1]) + (ax[2] + ax[3]);
    float oy = xty + (ay[0] + ay[1]) + (ay[2] + ay[3]);

    if (DST_BF) {
        ((unsigned*)dst)[(size_t)row * 64 + lane] = f2bf(ox) | (f2bf(oy) << 16);
    } else {
        float2 o; o.x = ox; o.y = oy;
        ((float2*)dst)[(size_t)row * 64 + lane] = o;
    }
}

// ---------- fallback (R0 atomic path) if ws too small ----------

__global__ __launch_bounds__(256) void init_step(const float4* __restrict__ x,
                                                 float4* __restrict__ dst, int n4) {
    int i = blockIdx.x * 256 + threadIdx.x;
    if (i < n4) {
        float4 v = x[i];
        dst[i] = make_float4(ALPHA * v.x, ALPHA * v.y, ALPHA * v.z, ALPHA * v.w);
    }
}

__global__ __launch_bounds__(256) void edge_scatter(const int* __restrict__ rows,
                                                    const int* __restrict__ cols,
                                                    const float* __restrict__ w,
                                                    const float* __restrict__ h,
                                                    float* __restrict__ dst) {
    unsigned t = blockIdx.x * 256u + threadIdx.x;
    unsigned e = t >> 5;
    unsigned l = t & 31u;
    if (e >= N_EDGES) return;
    int r = rows[e];
    int c = cols[e];
    float we = (1.0f - ALPHA) * w[e];
    const float4* hc = (const float4*)(h + (size_t)c * D_FEAT);
    float4 v = hc[l];
    float* dr = dst + (size_t)r * D_FEAT + (size_t)l * 4;
    unsafeAtomicAdd(dr + 0, we * v.x);
    unsafeAtomicAdd(dr + 1, we * v.y);
    unsafeAtomicAdd(dr + 2, we * v.z);
    unsafeAtomicAdd(dr + 3, we * v.w);
}

extern "C" void kernel_launch(void* const* d_in, const int* in_sizes, int n_in,
                              void* d_out, int out_size, void* d_ws, size_t ws_size,
                              hipStream_t stream) {
    const float* x  = (const float*)d_in[0];
    const int*   ei = (const int*)d_in[1];  // [2, E] flat: rows then cols
    const float* ev = (const float*)d_in[2];
    const int* rows = ei;
    const int* cols = ei + N_EDGES;
    float* out = (float*)d_out;

    auto align16 = [](size_t o) { return (o + 15) & ~(size_t)15; };

    // --- padded layout (tier 1): ha, cnt+gcount, csrp, hb, xb (contiguous) ---
    // gbuf (pass-A bucket buffer, 50.2 MB) aliases [hb, xb) which are dead
    // during the build; x_to_bf16 runs after bucket_to_csr in stream order.
    size_t p_off = 0;
    size_t p_ha   = p_off; p_off = align16(p_off + (size_t)N_NODES * D_FEAT * 2);
    size_t p_cnt  = p_off; p_off = align16(p_off + (size_t)N_NODES * 4 + NBUCK * 4);
    size_t p_csr  = p_off; p_off = align16(p_off + (size_t)N_NODES * MAXDEG * 8);
    size_t p_hb   = p_off; p_off = align16(p_off + (size_t)N_NODES * D_FEAT * 2);
    size_t p_xb   = p_off; p_off = align16(p_off + (size_t)N_NODES * D_FEAT * 2);
    size_t need_pad = p_off;  // ~128.6 MB
    static_assert((size_t)NBUCK * BCAP * 16 <= 2 * (size_t)N_NODES * D_FEAT * 2,
                  "gbuf must fit in hb+xb");

    // --- compact layout (tiers 2/3): ha, hb, rowptr, cursor, partial, csr, [xb] ---
    size_t c_off = 0;
    size_t c_ha      = c_off; c_off = align16(c_off + (size_t)N_NODES * D_FEAT * 2);
    size_t c_hb      = c_off; c_off = align16(c_off + (size_t)N_NODES * D_FEAT * 2);
    size_t c_rowptr  = c_off; c_off = align16(c_off + (size_t)(N_NODES + 1) * 4);
    size_t c_cursor  = c_off; c_off = align16(c_off + (size_t)N_NODES * 4);
    size_t c_partial = c_off; c_off = align16(c_off + (size_t)SCAN_NBLK * 4);
    size_t c_csr     = c_off; c_off = align16(c_off + (size_t)N_EDGES * 8);
    size_t need_base = c_off;  // ~64.8 MB
    size_t c_xb      = c_off; c_off = align16(c_off + (size_t)N_NODES * D_FEAT * 2);
    size_t need_xb   = c_off;  // ~90.4 MB

    const int row_blocks = (N_NODES * 64 + 255) / 256;  // 25000 (1 wave/row)
    const float2* x2 = (const float2*)x;

    if (ws_size >= need_pad) {
        // ---- tier 1: bucketed padded CSR build ----
        char* ws = (char*)d_ws;
        void*     h_a    = (void*)(ws + p_ha);
        int*      cnt    = (int*)(ws + p_cnt);
        int*      gcount = cnt + N_NODES;
        int2*     csrp   = (int2*)(ws + p_csr);
        void*     h_b    = (void*)(ws + p_hb);
        unsigned* xb     = (unsigned*)(ws + p_xb);
        int4*     gbuf   = (int4*)(ws + p_hb);  // aliases hb+xb during build

        hipMemsetAsync(cnt, 0, (size_t)N_NODES * 4 + NBUCK * 4, stream);
        const int blocks_a = (N_EDGES + EPB_A - 1) / EPB_A;  // 782
        bucket_scatter<<<blocks_a, 256, 0, stream>>>(rows, cols, ev, gcount, gbuf);
        bucket_to_csr<<<64, 256, 0, stream>>>(gcount, gbuf, cnt, csrp);

        const int nxb = N_NODES * D_FEAT / 2;
        x_to_bf16<<<(nxb + 255) / 256, 256, 0, stream>>>(x2, xb, nxb);

        row_spmm_t<true, true, true, true><<<row_blocks, 256, 0, stream>>>(
            cnt, csrp, (const void*)xb, (const void*)xb, h_a);
        for (int k = 1; k <= 8; ++k) {
            const void* src = (k & 1) ? h_a : h_b;
            void* dst = (k & 1) ? h_b : h_a;
            row_spmm_t<true, true, true, true><<<row_blocks, 256, 0, stream>>>(
                cnt, csrp, (const void*)xb, src, dst);
        }
        row_spmm_t<true, false, false, true><<<row_blocks, 256, 0, stream>>>(
            cnt, csrp, (const void*)x2, (const void*)h_a, (void*)out);
    } else if (ws_size >= need_base) {
        // ---- tiers 2/3: compact CSR (R5 path) ----
        char* ws = (char*)d_ws;
        void*  h_a     = (void*)(ws + c_ha);
        void*  h_b     = (void*)(ws + c_hb);
        int*   row_ptr = (int*)(ws + c_rowptr);
        int*   cursor  = (int*)(ws + c_cursor);
        int*   partial = (int*)(ws + c_partial);
        int2*  csr     = (int2*)(ws + c_csr);
        unsigned* xb   = (unsigned*)(ws + c_xb);
        const bool has_xb = (ws_size >= need_xb);
        const int edge_blocks_1t = (N_EDGES + 255) / 256;  // 6250

        hipMemsetAsync(cursor, 0, (size_t)N_NODES * 4, stream);
        hist_kernel<<<edge_blocks_1t, 256, 0, stream>>>(rows, cursor);
        scan_partial<<<SCAN_NBLK, 256, 0, stream>>>(cursor, partial);
        scan_top<<<1, 256, 0, stream>>>(partial);
        scan_final<<<SCAN_NBLK, 256, 0, stream>>>(cursor, partial, row_ptr);
        scatter_kernel<<<edge_blocks_1t, 256, 0, stream>>>(rows, cols, ev, cursor, csr);

        if (has_xb) {
            const int nxb = N_NODES * D_FEAT / 2;
            x_to_bf16<<<(nxb + 255) / 256, 256, 0, stream>>>(x2, xb, nxb);
            row_spmm_t<true, true, true, false><<<row_blocks, 256, 0, stream>>>(
                row_ptr, csr, (const void*)xb, (const void*)xb, h_a);
            for (int k = 1; k <= 8; ++k) {
                const void* src = (k & 1) ? h_a : h_b;
                void* dst = (k & 1) ? h_b : h_a;
                row_spmm_t<true, true, true, false><<<row_blocks, 256, 0, stream>>>(
                    row_ptr, csr, (const void*)xb, src, dst);
            }
            row_spmm_t<true, false, false, false><<<row_blocks, 256, 0, stream>>>(
                row_ptr, csr, (const void*)x2, (const void*)h_a, (void*)out);
        } else {
            row_spmm_t<false, true, false, false><<<row_blocks, 256, 0, stream>>>(
                row_ptr, csr, (const void*)x2, (const void*)x, h_a);
            for (int k = 1; k <= 8; ++k) {
                const void* src = (k & 1) ? h_a : h_b;
                void* dst = (k & 1) ? h_b : h_a;
                row_spmm_t<true, true, false, false><<<row_blocks, 256, 0, stream>>>(
                    row_ptr, csr, (const void*)x2, src, dst);
            }
            row_spmm_t<true, false, false, false><<<row_blocks, 256, 0, stream>>>(
                row_ptr, csr, (const void*)x2, (const void*)h_a, (void*)out);
        }
    } else {
        // Fallback: R0 atomic path (needs only the 51.2 MB ping buffer)
        float* wsf = (float*)d_ws;
        const int n4 = N_NODES * D_FEAT / 4;
        const int init_blocks = (n4 + 255) / 256;
        const int edge_blocks = (N_EDGES * 32 + 255) / 256;
        for (int k = 0; k < K_STEPS; ++k) {
            const float* src = (k == 0) ? x : ((k & 1) ? wsf : out);
            float* dst = (k & 1) ? out : wsf;
            init_step<<<init_blocks, 256, 0, stream>>>((const float4*)x, (float4*)dst, n4);
            edge_scatter<<<edge_blocks, 256, 0, stream>>>(rows, cols, ev, src, dst);
        }
    }
}